// Round 5
// baseline (200.719 us; speedup 1.0000x reference)
//
#include <hip/hip_runtime.h>

// HoloAttentionV2: prep -> x@[Wk|Wv] (256x256, 2-phase/K-tile, 32 MFMA/phase)
// -> scan_part -> scan_out -> y@Wo (256x128 variant, full-GPU). 5 launches.
// B=2 T=4096 DM=1024 H=16 D=64, M=8192, K=1024 both GEMMs.

#define B_ 2
#define T_ 4096
#define H_ 16
#define D_ 64
#define M_ (B_*T_)
#define PHASE_SCALE 10.0f

typedef _Float16 f16;
typedef unsigned int u32;
typedef __attribute__((ext_vector_type(8))) _Float16 f16x8;
typedef __attribute__((ext_vector_type(4))) _Float16 f16x4;
typedef __attribute__((ext_vector_type(4))) float f32x4;

// ---------------- prep: z<3 weight transpose-cvt, z==3 x cvt ----------------

__global__ void k_prep(const float* __restrict__ x, const float* __restrict__ Wk,
                       const float* __restrict__ Wv, const float* __restrict__ Wo,
                       f16* __restrict__ xh, f16* __restrict__ Wkvt, f16* __restrict__ Wot) {
  __shared__ float tile[32][33];
  const int z = blockIdx.z;
  const int tx = threadIdx.x, ty = threadIdx.y;
  if (z == 3) {
    const int blk = blockIdx.y * 32 + blockIdx.x;
    const size_t base = (size_t)blk * 256 + ty * 32 + tx;
    #pragma unroll
    for (int i = 0; i < 8; ++i) {
      size_t idx = (base + (size_t)i * 262144) * 4;
      float4 v = *reinterpret_cast<const float4*>(x + idx);
      f16x4 o; o[0] = (f16)v.x; o[1] = (f16)v.y; o[2] = (f16)v.z; o[3] = (f16)v.w;
      *reinterpret_cast<f16x4*>(xh + idx) = o;
    }
    return;
  }
  const float* src = (z == 0) ? Wk : (z == 1) ? Wv : Wo;
  f16* dst = (z == 0) ? Wkvt : (z == 1) ? (Wkvt + (size_t)1024 * 1024) : Wot;
  const int bx = blockIdx.x, by = blockIdx.y;
  #pragma unroll
  for (int r = 0; r < 32; r += 8)
    tile[ty + r][tx] = src[(size_t)(by * 32 + ty + r) * 1024 + bx * 32 + tx];
  __syncthreads();
  #pragma unroll
  for (int r = 0; r < 32; r += 8)
    dst[(size_t)(bx * 32 + ty + r) * 1024 + by * 32 + tx] = (f16)tile[tx][ty + r];
}

// ---------------- 2-phase/K-tile f16 MFMA GEMM, K=1024 (16 K-tiles of 64) ----
// template NJ: col-frags per (bh,wc). NJ=2 -> BN=256 (G1); NJ=1 -> BN=128 (G2).
// BM=256 fixed. A: M x 1024 f16. Bt: N x 1024 f16. C col<1024 -> C32; else C16.
// 8 waves (wr=wid>>2 in {0,1}, wc=wid&3). Wave rows: ah*128 + wr*64 + mi*16
// (mi 0..3); cols: bh*(64*NJ) + wc*(16*NJ) + nj*16.
// Phase p0: read A0 frags (8 b128) + ALL B frags (cached) -> 32*NJ/2... MFMA
// ah=0; p1: read A1 frags -> MFMA ah=1. 32 phases total (vs 64 in round 4) --
// doubles MFMA per fixed phase overhead (the measured 2x gap vs m201).
// LDS per buffer: [A0 16K | A1 16K | B0 BHB | B1 BHB], double-buffered.
// Stage schedule (region staged only AFTER its last-read phase, barrier-sep):
//   p0(kt): A1(kt+1), B1(kt+1) -> nxtbuf (not read this K-tile: safe)
//   p1(kt): A0(kt+2), B0(kt+2) -> curbuf (A0/B0 last read at p0: safe)
// vmcnt ledger (groups: A=2, B=NJ instr): steady wait at p1 end drains through
// kt.p0's group, leaving kt.p1's -> vm4 (NJ=2) / vm3 (NJ=1). Prologue stages
// A0(0) B0(0) A1(0) B1(0) A0(1) B0(1), wait leaves last 2 groups -> vm4/vm3.
// Tail kt=14: p1 stages nothing -> vm0; kt=15: no stages, no waits.

__device__ __forceinline__ void gl2lds16(const f16* g, char* l) {
  __builtin_amdgcn_global_load_lds((const __attribute__((address_space(1))) u32*)g,
                                   (__attribute__((address_space(3))) u32*)l, 16, 0, 0);
}

#define S_BAR() __builtin_amdgcn_s_barrier()
#define WAIT_LGKM0() do { asm volatile("s_waitcnt lgkmcnt(0)" ::: "memory"); \
                          __builtin_amdgcn_sched_barrier(0); } while (0)
#define WAIT_VM(n) asm volatile("s_waitcnt vmcnt(" #n ")" ::: "memory")

#define STA(gp, ldsoff, kkt) do { \
  gl2lds16((gp) + (size_t)(kkt) * 64,              smem + (ldsoff) + tid * 16); \
  gl2lds16((gp) + (size_t)(kkt) * 64 + 64 * 1024,  smem + (ldsoff) + 8192 + tid * 16); \
} while (0)
#define STB(gp, ldsoff, kkt) do { \
  gl2lds16((gp) + (size_t)(kkt) * 64,              smem + (ldsoff) + tid * 16); \
  if constexpr (NJ == 2) \
    gl2lds16((gp) + (size_t)(kkt) * 64 + 64 * 1024, smem + (ldsoff) + 8192 + tid * 16); \
} while (0)

// p0: read A0 + all B, MFMA ah=0
#define PH0(CUR, STG) do { \
  _Pragma("unroll") for (int mi = 0; mi < 4; ++mi) \
  _Pragma("unroll") for (int kk = 0; kk < 2; ++kk) \
    aF[mi][kk] = *(const f16x8*)(smem + (CUR) + offA[mi][kk]); \
  _Pragma("unroll") for (int bh = 0; bh < 2; ++bh) \
  _Pragma("unroll") for (int nj = 0; nj < NJ; ++nj) \
  _Pragma("unroll") for (int kk = 0; kk < 2; ++kk) \
    bF[bh][nj][kk] = *(const f16x8*)(smem + (CUR) + OFF_B0 + bh * BHB + offB[nj][kk]); \
  STG; \
  S_BAR(); \
  WAIT_LGKM0(); \
  __builtin_amdgcn_s_setprio(1); \
  _Pragma("unroll") for (int bh = 0; bh < 2; ++bh) \
  _Pragma("unroll") for (int mi = 0; mi < 4; ++mi) \
  _Pragma("unroll") for (int nj = 0; nj < NJ; ++nj) \
  _Pragma("unroll") for (int kk = 0; kk < 2; ++kk) \
    acc[bh][mi][nj] = __builtin_amdgcn_mfma_f32_16x16x32_f16( \
        aF[mi][kk], bF[bh][nj][kk], acc[bh][mi][nj], 0, 0, 0); \
  __builtin_amdgcn_s_setprio(0); \
  S_BAR(); \
} while (0)

// p1: read A1 (B cached), MFMA ah=1, then VMW before end barrier
#define PH1(CUR, STG, VMW) do { \
  _Pragma("unroll") for (int mi = 0; mi < 4; ++mi) \
  _Pragma("unroll") for (int kk = 0; kk < 2; ++kk) \
    aF[mi][kk] = *(const f16x8*)(smem + (CUR) + 16384 + offA[mi][kk]); \
  STG; \
  S_BAR(); \
  WAIT_LGKM0(); \
  __builtin_amdgcn_s_setprio(1); \
  _Pragma("unroll") for (int bh = 0; bh < 2; ++bh) \
  _Pragma("unroll") for (int mi = 0; mi < 4; ++mi) \
  _Pragma("unroll") for (int nj = 0; nj < NJ; ++nj) \
  _Pragma("unroll") for (int kk = 0; kk < 2; ++kk) \
    acc[2 + bh][mi][nj] = __builtin_amdgcn_mfma_f32_16x16x32_f16( \
        aF[mi][kk], bF[bh][nj][kk], acc[2 + bh][mi][nj], 0, 0, 0); \
  __builtin_amdgcn_s_setprio(0); \
  VMW; \
  S_BAR(); \
} while (0)

template<int NJ>
__launch_bounds__(512, 1)
__global__ void k_gemm2p(const f16* __restrict__ A, const f16* __restrict__ Bt,
                         float* __restrict__ C32, f16* __restrict__ C16) {
  extern __shared__ char smem[];
  constexpr int BHR    = NJ * 64;            // B half-tile rows
  constexpr int BHB    = BHR * 128;          // B half-tile bytes
  constexpr int OFF_B0 = 32768;
  constexpr int BUFSZ  = 32768 + 2 * BHB;
  const int tid  = threadIdx.x;
  const int lane = tid & 63;
  const int wid  = tid >> 6;
  const int wr   = wid >> 2, wc = wid & 3;
  const int lr   = lane & 15, hi = lane >> 4;
  const int m0   = blockIdx.x * 256;
  const int n0   = blockIdx.y * (NJ * 128);

  const int rsub = tid >> 3;
  const int csw  = ((tid & 7) ^ (rsub & 7)) * 8;   // pre-swizzled source chunk
  const f16* gA0 = A  + (size_t)(m0 + rsub) * 1024 + csw;
  const f16* gA1 = gA0 + (size_t)128 * 1024;
  const f16* gB0 = Bt + (size_t)(n0 + rsub) * 1024 + csw;
  const f16* gB1 = gB0 + (size_t)BHR * 1024;

  int offA[4][2], offB[NJ][2];
  #pragma unroll
  for (int mi = 0; mi < 4; ++mi)
    #pragma unroll
    for (int kk = 0; kk < 2; ++kk) {
      int row = wr * 64 + mi * 16 + lr;            // 0..127 within A half
      offA[mi][kk] = row * 128 + (((kk * 4 + hi) ^ (row & 7)) << 4);
    }
  #pragma unroll
  for (int nj = 0; nj < NJ; ++nj)
    #pragma unroll
    for (int kk = 0; kk < 2; ++kk) {
      int row = wc * (16 * NJ) + nj * 16 + lr;     // 0..BHR-1 within B half
      offB[nj][kk] = row * 128 + (((kk * 4 + hi) ^ (row & 7)) << 4);
    }

  f32x4 acc[4][4][NJ] = {};     // [ah*2+bh][mi][nj]
  f16x8 aF[4][2], bF[2][NJ][2]; // bF cached across p0/p1

  // prologue
  STA(gA0, 0,                0);
  STB(gB0, OFF_B0,           0);
  STA(gA1, 16384,            0);
  STB(gB1, OFF_B0 + BHB,     0);
  STA(gA0, BUFSZ,            1);
  STB(gB0, BUFSZ + OFF_B0,   1);
  if constexpr (NJ == 2) WAIT_VM(4); else WAIT_VM(3);
  S_BAR();

  for (int kt = 0; kt < 14; ++kt) {
    const int cur = (kt & 1) * BUFSZ;
    const int nxt = cur ^ BUFSZ;
    PH0(cur, { STA(gA1, nxt + 16384, kt + 1); STB(gB1, nxt + OFF_B0 + BHB, kt + 1); });
    PH1(cur, { STA(gA0, cur, kt + 2); STB(gB0, cur + OFF_B0, kt + 2); },
        if constexpr (NJ == 2) WAIT_VM(4); else WAIT_VM(3));
  }
  { // kt = 14
    const int cur = 0, nxt = BUFSZ;
    PH0(cur, { STA(gA1, nxt + 16384, 15); STB(gB1, nxt + OFF_B0 + BHB, 15); });
    PH1(cur, (void)0, WAIT_VM(0));
  }
  { // kt = 15
    const int cur = BUFSZ;
    PH0(cur, (void)0);
    PH1(cur, (void)0, (void)0);
  }

  // epilogue: C/D layout col=lane&15, row=(lane>>4)*4+reg (m89-verified)
  const int rb = hi * 4;
  #pragma unroll
  for (int ah = 0; ah < 2; ++ah)
    #pragma unroll
    for (int bh = 0; bh < 2; ++bh)
      #pragma unroll
      for (int mi = 0; mi < 4; ++mi)
        #pragma unroll
        for (int nj = 0; nj < NJ; ++nj) {
          f32x4 a4 = acc[ah * 2 + bh][mi][nj];
          const int row = m0 + ah * 128 + wr * 64 + mi * 16 + rb;
          const int col = n0 + bh * (64 * NJ) + wc * (16 * NJ) + nj * 16 + lr;
          if (col < 1024) {
            #pragma unroll
            for (int r = 0; r < 4; ++r)
              C32[(size_t)(row + r) * 1024 + col] = a4[r];
          } else {
            #pragma unroll
            for (int r = 0; r < 4; ++r)
              C16[(size_t)(row + r) * 1024 + (col - 1024)] = (f16)a4[r];
          }
        }
}

// ---------------- scan: 64 chunks x 64 t; lane = d, wave = chunk -------------

__global__ void k_scan_part(const float* __restrict__ kf, const f16* __restrict__ vh,
                            const float* __restrict__ freqs, float4* __restrict__ tot) {
  const int bid = blockIdx.x;
  const int cg = bid & 15;
  const int h  = (bid >> 4) & 15;
  const int b  = bid >> 8;
  const int w  = threadIdx.x >> 6;
  const int d  = threadIdx.x & 63;
  const int c  = cg * 4 + w;
  const int t0 = c * 64;
  const int col = h * 64 + d;
  const float f = freqs[col];

  float bc = 0.f, bs = 0.f;
  if (t0 > 0) {
    float krp = kf[(size_t)(b * T_ + t0 - 1) * 1024 + col];
    __sincosf(PHASE_SCALE * krp, &bs, &bc);
  }
  double rev = (double)t0 * (double)f * 0.15915494309189535;
  rev -= floor(rev);
  float ph = (float)rev * 6.28318530717958647692f;
  float ri, rc; __sincosf(ph, &ri, &rc);
  float sf, cf; __sincosf(f, &sf, &cf);

  float pr = 0.f, pi = 0.f, ar = 0.f, ai = 0.f;
  #pragma unroll 4
  for (int tt = 0; tt < 64; ++tt) {
    size_t row = (size_t)(b * T_ + t0 + tt) * 1024 + col;
    float v  = (float)vh[row];
    float kr = kf[row];
    pr = fmaf(v, rc, pr); pi = fmaf(v, ri, pi);
    ar = fmaf(v, bc, ar); ai = fmaf(-v, bs, ai);
    __sincosf(PHASE_SCALE * kr, &bs, &bc);
    float nrc = rc * cf - ri * sf;
    ri = rc * sf + ri * cf; rc = nrc;
  }
  tot[((size_t)(c * 2 + b) * 16 + h) * 64 + d] = make_float4(pr, pi, ar, ai);
}

__global__ void k_scan_out(const float* __restrict__ kf, const f16* __restrict__ vh,
                           const float* __restrict__ freqs, const float4* __restrict__ tot,
                           const float* __restrict__ gate, f16* __restrict__ y) {
  const int bid = blockIdx.x;
  const int cg = bid & 15;
  const int h  = (bid >> 4) & 15;
  const int b  = bid >> 8;
  const int w  = threadIdx.x >> 6;
  const int d  = threadIdx.x & 63;
  const int c  = cg * 4 + w;
  const int t0 = c * 64;
  const int col = h * 64 + d;
  const float f = freqs[col];
  const float gp = gate[2 * h], ga = gate[2 * h + 1];

  float pr = 0.f, pi = 0.f, ar = 0.f, ai = 0.f;
  for (int cc = 0; cc < c; ++cc) {
    float4 tv = tot[((size_t)(cc * 2 + b) * 16 + h) * 64 + d];
    pr += tv.x; pi += tv.y; ar += tv.z; ai += tv.w;
  }

  float bc = 0.f, bs = 0.f;
  if (t0 > 0) {
    float krp = kf[(size_t)(b * T_ + t0 - 1) * 1024 + col];
    __sincosf(PHASE_SCALE * krp, &bs, &bc);
  }
  double rev = (double)t0 * (double)f * 0.15915494309189535;
  rev -= floor(rev);
  float ph = (float)rev * 6.28318530717958647692f;
  float ri, rc; __sincosf(ph, &ri, &rc);
  float sf, cf; __sincosf(f, &sf, &cf);

  #pragma unroll 4
  for (int tt = 0; tt < 64; ++tt) {
    int t = t0 + tt;
    size_t row = (size_t)(b * T_ + t) * 1024 + col;
    float v  = (float)vh[row];
    float kr = kf[row];
    pr = fmaf(v, rc, pr); pi = fmaf(v, ri, pi);
    ar = fmaf(v, bc, ar); ai = fmaf(-v, bs, ai);
    float kc, ks; __sincosf(PHASE_SCALE * kr, &ks, &kc);
    float inv = rsqrtf((float)(t + 1));
    float op = fmaf(pr, rc, pi * ri) * inv;
    float oa = fmaf(ar, kc, -(ai * ks)) * inv;
    y[row] = (f16)(gp * op + ga * oa);
    bs = ks; bc = kc;
    float nrc = rc * cf - ri * sf;
    ri = rc * sf + ri * cf; rc = nrc;
  }
}

// ---------------- launch ----------------

extern "C" void kernel_launch(void* const* d_in, const int* in_sizes, int n_in,
                              void* d_out, int out_size, void* d_ws, size_t ws_size,
                              hipStream_t stream) {
  const float* x     = (const float*)d_in[0];
  const float* Wk    = (const float*)d_in[1];
  const float* Wv    = (const float*)d_in[2];
  const float* Wo    = (const float*)d_in[3];
  const float* gate  = (const float*)d_in[4];
  const float* freqs = (const float*)d_in[5];
  float* out = (float*)d_out;

  char* ws = (char*)d_ws;
  size_t off = 0;
  auto alloc = [&](size_t bytes) { void* p = ws + off; off += (bytes + 255) & ~255ull; return p; };

  f16*    xh   = (f16*)   alloc((size_t)M_ * 1024 * sizeof(f16));   // aliased as y
  f16*    Wkvt = (f16*)   alloc((size_t)2048 * 1024 * sizeof(f16));
  f16*    Wot  = (f16*)   alloc((size_t)1024 * 1024 * sizeof(f16));
  float*  kf   = (float*) alloc((size_t)M_ * 1024 * sizeof(float));
  f16*    vh   = (f16*)   alloc((size_t)M_ * 1024 * sizeof(f16));
  float4* tot  = (float4*)alloc((size_t)64 * B_ * H_ * D_ * sizeof(float4));
  f16*    yh   = xh;  // xh last read by GEMM1; scan_out writes y after

  hipFuncSetAttribute(reinterpret_cast<const void*>(&k_gemm2p<2>),
                      hipFuncAttributeMaxDynamicSharedMemorySize, 131072);
  hipFuncSetAttribute(reinterpret_cast<const void*>(&k_gemm2p<1>),
                      hipFuncAttributeMaxDynamicSharedMemorySize, 98304);

  hipLaunchKernelGGL(k_prep, dim3(32, 32, 4), dim3(32, 8), 0, stream,
                     x, Wk, Wv, Wo, xh, Wkvt, Wot);
  // [k_real | v] = x @ [Wk | Wv]
  hipLaunchKernelGGL(k_gemm2p<2>, dim3(32, 8), dim3(512), 131072, stream, xh, Wkvt, kf, vh);
  hipLaunchKernelGGL(k_scan_part, dim3(512), dim3(256), 0, stream, kf, vh, freqs, tot);
  hipLaunchKernelGGL(k_scan_out,  dim3(512), dim3(256), 0, stream, kf, vh, freqs, tot, gate, yh);
  // out = y @ Wo  (BN=128 -> grid 32x8 = 256 blocks, full GPU)
  hipLaunchKernelGGL(k_gemm2p<1>, dim3(32, 8), dim3(512), 98304, stream, yh, Wot, out, nullptr);
}